// Round 4
// baseline (132.082 us; speedup 1.0000x reference)
//
#include <hip/hip_runtime.h>
#include <hip/hip_fp16.h>

typedef _Float16 half_t;
typedef __attribute__((ext_vector_type(8))) _Float16 half8;
typedef __attribute__((ext_vector_type(4))) _Float16 half4;
typedef __attribute__((ext_vector_type(4))) float floatx4;

#define NJ 24
#define IN_DIM 256
#define HID 128
#define OUT_DIM 6
#define BATCH 16384
#define BM 64   // rows per block (4 waves x 16 rows)

// ws layout (half elements): W1 [j][ks8][n128][kk32], W2 [j][ks4][n128][kk32],
// W3 [j][n16pad][k128], then f32 b3 padded to 16.
#define W1_JSTRIDE (8 * 128 * 32)   // 32768 halves = 64KB
#define W2_JSTRIDE (4 * 128 * 32)   // 16384 halves = 32KB
#define W3_JSTRIDE (16 * 128)       // 2048 halves  = 4KB
#define WT1_ELEMS (NJ * W1_JSTRIDE)
#define WT2_ELEMS (NJ * W2_JSTRIDE)
#define WT3_ELEMS (NJ * W3_JSTRIDE)
#define WT2_OFF WT1_ELEMS
#define WT3_OFF (WT1_ELEMS + WT2_ELEMS)
#define B3P_BYTE_OFF ((size_t)(WT1_ELEMS + WT2_ELEMS + WT3_ELEMS) * 2)
#define PREP_TOTAL (WT1_ELEMS + WT2_ELEMS + WT3_ELEMS + NJ * 16)

// ---------------------------------------------------------------------------
// Prep: f32 -> f16, chunk-major transposed layouts (proven in R2).
// ---------------------------------------------------------------------------
__global__ void posemlp_prep(const float* __restrict__ W1, const float* __restrict__ W2,
                             const float* __restrict__ W3, const float* __restrict__ b3,
                             half_t* __restrict__ wt, float* __restrict__ b3p) {
    int t = blockIdx.x * 256 + threadIdx.x;
    if (t < WT1_ELEMS) {
        int j = t / W1_JSTRIDE, r = t % W1_JSTRIDE;
        int ks = r / 4096, r2 = r % 4096;
        int n = r2 / 32, kk = r2 % 32, k = ks * 32 + kk;
        wt[t] = (half_t)W1[((size_t)j * IN_DIM + k) * HID + n];
    } else if (t < WT2_OFF + WT2_ELEMS) {
        int u = t - WT2_OFF;
        int j = u / W2_JSTRIDE, r = u % W2_JSTRIDE;
        int ks = r / 4096, r2 = r % 4096;
        int n = r2 / 32, kk = r2 % 32, k = ks * 32 + kk;
        wt[t] = (half_t)W2[((size_t)j * HID + k) * HID + n];
    } else if (t < WT3_OFF + WT3_ELEMS) {
        int u = t - WT3_OFF;
        int j = u / W3_JSTRIDE, r = u % W3_JSTRIDE;
        int n = r / 128, k = r % 128;
        wt[t] = (n < OUT_DIM) ? (half_t)W3[((size_t)j * HID + k) * OUT_DIM + n] : (half_t)0.0f;
    } else if (t < PREP_TOTAL) {
        int u = t - WT3_OFF - WT3_ELEMS;
        int j = u / 16, n = u % 16;
        b3p[u] = (n < OUT_DIM) ? b3[j * OUT_DIM + n] : 0.0f;
    }
}

// ---------------------------------------------------------------------------
// helpers (no inline asm anywhere — correctness is pure dataflow + barriers)
// ---------------------------------------------------------------------------
__device__ inline void gll16(const void* g, void* l) {
    __builtin_amdgcn_global_load_lds(
        (const __attribute__((address_space(1))) unsigned int*)g,
        (__attribute__((address_space(3))) unsigned int*)l, 16, 0, 0);
}

// h LDS: [row 0..63][n 0..127] f16, pitch 256B, XOR-swizzled (proven R2).
__device__ inline half8 lds_read8(const half_t* lds, int r, int k) {
    int byte = r * 256 + k * 2;
    byte ^= (r & 7) << 4;
    return *(const half8*)((const char*)lds + byte);
}
__device__ inline void lds_write4(half_t* lds, int r, int n, half4 v) {
    int byte = r * 256 + n * 2;
    byte ^= (r & 7) << 4;
    *(half4*)((char*)lds + byte) = v;
}

__device__ inline half8 cvt8(floatx4 a, floatx4 b) {
    half8 h;
    h[0] = (_Float16)a[0]; h[1] = (_Float16)a[1]; h[2] = (_Float16)a[2]; h[3] = (_Float16)a[3];
    h[4] = (_Float16)b[0]; h[5] = (_Float16)b[1]; h[6] = (_Float16)b[2]; h[7] = (_Float16)b[3];
    return h;
}

// ---------------------------------------------------------------------------
// Main: 256 threads (4 waves), BM=64 rows, 3-phase bulk weight staging.
//   P0: stage W1[k0:4]+W3, prefetch X0-2     -> sync
//   A : L1 ks=0..3                           -> sync, stage W1[k4:8], sync
//   B : L1 ks=4..7, h1 epilogue              -> sync, stage W2,       sync
//   L2: ks=0..3, h2 epilogue; L3; store.  h rows are wave-private.
// X prefetch: rotating px[3], READ-then-refill (R3 bug fixed).
// ---------------------------------------------------------------------------
__global__ __launch_bounds__(256, 3) void posemlp_main(
    const float* __restrict__ X, const half_t* __restrict__ wt,
    const float* __restrict__ b1, const float* __restrict__ b2,
    const float* __restrict__ b3p, float* __restrict__ out) {
    __shared__ half_t wbuf[16384];     // 32KB: 4 chunks of [n128][kk32]
    __shared__ half_t w3buf[2048];     // 4KB
    __shared__ half_t h_lds[BM * HID]; // 16KB   -> 52KB total, 3 blocks/CU

    const int bid0 = blockIdx.x;
    const int bid = (bid0 & 7) * 768 + (bid0 >> 3);  // XCD swizzle (6144 = 8*768)
    const int j = bid >> 8;
    const int row0 = (bid & 255) * BM;
    const int tid = threadIdx.x;
    const int w = tid >> 6;
    const int l = tid & 63;
    const int lrow = l & 15;
    const int q = l >> 4;
    const int myrow = w * 16 + lrow;

    const float* xq = X + ((size_t)(row0 + myrow) * NJ + j) * IN_DIM + q * 8;

    const half_t* w1j = wt + (size_t)j * W1_JSTRIDE;
    const half_t* w2j = wt + WT2_OFF + (size_t)j * W2_JSTRIDE;
    const half_t* w3j = wt + WT3_OFF + (size_t)j * W3_JSTRIDE;

    // stage-source index (per lane; XOR pre-swizzle on the 16B source slot).
    // round r covers linear rows [r*64, r*64+64); sn = row mod 64, and the
    // swizzle uses row bits [1:2], identical on stage and read side.
    const int sn = tid >> 2, ss = tid & 3;
    const int wsrc = sn * 32 + (ss ^ ((sn >> 1) & 3)) * 8;  // halves

    // --- P0: X prefetch + stage W3 + W1 first half ---
    floatx4 px[3][2];
    px[0][0] = *(const floatx4*)(xq);
    px[0][1] = *(const floatx4*)(xq + 4);
    px[1][0] = *(const floatx4*)(xq + 32);
    px[1][1] = *(const floatx4*)(xq + 36);
    px[2][0] = *(const floatx4*)(xq + 64);
    px[2][1] = *(const floatx4*)(xq + 68);
    {
        const int tn = tid >> 4, tsl = tid & 15;
        gll16(w3j + tn * 128 + (tsl ^ tn) * 8, &w3buf[w * 512]);
    }
#pragma unroll
    for (int r = 0; r < 8; ++r)
        gll16(w1j + r * 2048 + wsrc, &wbuf[r * 2048 + w * 512]);
    __syncthreads();

// one L1 iteration: read px slot FIRST, then refill it (depth-3 rotation)
#define L1_ITER(ks, wbbase) do {                                            \
        half8 bx = cvt8(px[(ks) % 3][0], px[(ks) % 3][1]);                  \
        if ((ks) < 5) {                                                     \
            px[(ks) % 3][0] = *(const floatx4*)(xq + ((ks) + 3) * 32);      \
            px[(ks) % 3][1] = *(const floatx4*)(xq + ((ks) + 3) * 32 + 4);  \
        }                                                                   \
        _Pragma("unroll")                                                   \
        for (int nf = 0; nf < 8; ++nf) {                                    \
            const int n = nf * 16 + lrow;                                   \
            half8 a = *(const half8*)&(wbbase)[n * 32 + (q ^ ((n >> 1) & 3)) * 8]; \
            acc[nf] = __builtin_amdgcn_mfma_f32_16x16x32_f16(a, bx, acc[nf], 0, 0, 0); \
        }                                                                   \
    } while (0)

    // --- phase A: L1 ks=0..3 ---
    floatx4 acc[8] = {};
#pragma unroll
    for (int ks = 0; ks < 4; ++ks) L1_ITER(ks, wbuf + ks * 4096);
    __syncthreads();                       // all waves done reading W1[k0:4]
#pragma unroll
    for (int r = 0; r < 8; ++r)
        gll16(w1j + 16384 + r * 2048 + wsrc, &wbuf[r * 2048 + w * 512]);
    __syncthreads();                       // W1[k4:8] landed

    // --- phase B: L1 ks=4..7 ---
#pragma unroll
    for (int ks = 4; ks < 8; ++ks) L1_ITER(ks, wbuf + (ks - 4) * 4096);
    {   // h1 = relu(acc + b1) -> LDS (wave-private rows)
        const float* b1j = b1 + j * HID;
#pragma unroll
        for (int nf = 0; nf < 8; ++nf) {
            floatx4 bb = *(const floatx4*)(b1j + nf * 16 + q * 4);
            floatx4 v = acc[nf];
            half4 hv;
#pragma unroll
            for (int i = 0; i < 4; ++i) hv[i] = (_Float16)fmaxf(v[i] + bb[i], 0.0f);
            lds_write4(h_lds, myrow, nf * 16 + q * 4, hv);
        }
    }
    __syncthreads();                       // all waves done reading W1[k4:8]
#pragma unroll
    for (int r = 0; r < 8; ++r)
        gll16(w2j + r * 2048 + wsrc, &wbuf[r * 2048 + w * 512]);
    __syncthreads();                       // W2 landed

    // --- Layer 2: K=128, 4 chunks, all in wbuf ---
    floatx4 acc2[8] = {};
#pragma unroll
    for (int ks = 0; ks < 4; ++ks) {
        half8 bh = lds_read8(h_lds, myrow, ks * 32 + q * 8);
#pragma unroll
        for (int nf = 0; nf < 8; ++nf) {
            const int n = nf * 16 + lrow;
            half8 a = *(const half8*)&wbuf[ks * 4096 + n * 32 + (q ^ ((n >> 1) & 3)) * 8];
            acc2[nf] = __builtin_amdgcn_mfma_f32_16x16x32_f16(a, bh, acc2[nf], 0, 0, 0);
        }
    }
    {   // h2 = relu(acc2 + b2) -> LDS (same wave-private rows; dataflow-ordered)
        const float* b2j = b2 + j * HID;
#pragma unroll
        for (int nf = 0; nf < 8; ++nf) {
            floatx4 bb = *(const floatx4*)(b2j + nf * 16 + q * 4);
            floatx4 v = acc2[nf];
            half4 hv;
#pragma unroll
            for (int i = 0; i < 4; ++i) hv[i] = (_Float16)fmaxf(v[i] + bb[i], 0.0f);
            lds_write4(h_lds, myrow, nf * 16 + q * 4, hv);
        }
    }

    // --- Layer 3: N padded to 16, K=128 ---
    floatx4 acc3 = {};
#pragma unroll
    for (int ks = 0; ks < 4; ++ks) {
        const int u = ks * 4 + q;
        half8 a3 = *(const half8*)&w3buf[lrow * 128 + (u ^ lrow) * 8];
        half8 bh = lds_read8(h_lds, myrow, ks * 32 + q * 8);
        acc3 = __builtin_amdgcn_mfma_f32_16x16x32_f16(a3, bh, acc3, 0, 0, 0);
    }
    {
        floatx4 bb = *(const floatx4*)(b3p + j * 16 + q * 4);
        const int orow = row0 + myrow;
        float* op = out + ((size_t)orow * NJ + j) * OUT_DIM;
        floatx4 v = acc3;
        if (q == 0) {
            float2 s0 = {v[0] + bb[0], v[1] + bb[1]};
            float2 s1 = {v[2] + bb[2], v[3] + bb[3]};
            *(float2*)(op + 0) = s0;
            *(float2*)(op + 2) = s1;
        } else if (q == 1) {
            float2 s = {v[0] + bb[0], v[1] + bb[1]};
            *(float2*)(op + 4) = s;
        }
    }
}

// ---------------------------------------------------------------------------
extern "C" void kernel_launch(void* const* d_in, const int* in_sizes, int n_in,
                              void* d_out, int out_size, void* d_ws, size_t ws_size,
                              hipStream_t stream) {
    const float* X  = (const float*)d_in[0];
    const float* W1 = (const float*)d_in[1];
    const float* b1 = (const float*)d_in[2];
    const float* W2 = (const float*)d_in[3];
    const float* b2 = (const float*)d_in[4];
    const float* W3 = (const float*)d_in[5];
    const float* b3 = (const float*)d_in[6];
    float* out = (float*)d_out;

    half_t* wt = (half_t*)d_ws;
    float* b3p = (float*)((char*)d_ws + B3P_BYTE_OFF);

    int prep_blocks = (PREP_TOTAL + 255) / 256;
    posemlp_prep<<<prep_blocks, 256, 0, stream>>>(W1, W2, W3, b3, wt, b3p);

    int grid = NJ * (BATCH / BM);  // 24 * 256 = 6144
    posemlp_main<<<grid, 256, 0, stream>>>(X, wt, b1, b2, b3p, out);
}

// Round 5
// 119.560 us; speedup vs baseline: 1.1047x; 1.1047x over previous
//
#include <hip/hip_runtime.h>
#include <hip/hip_fp16.h>

typedef _Float16 half_t;
typedef __attribute__((ext_vector_type(8))) _Float16 half8;
typedef __attribute__((ext_vector_type(4))) _Float16 half4;
typedef __attribute__((ext_vector_type(4))) float floatx4;

#define NJ 24
#define IN_DIM 256
#define HID 128
#define OUT_DIM 6
#define BATCH 16384
#define BM 64   // rows per block (4 waves x 16 rows)

// ws layout (half elements): W1 [j][ks8][n128][kk32], W2 [j][ks4][n128][kk32],
// W3 [j][n16pad][k128], then f32 b3 padded to 16.
#define W1_JSTRIDE (8 * 128 * 32)   // 32768 halves = 64KB
#define W2_JSTRIDE (4 * 128 * 32)   // 16384 halves = 32KB
#define W3_JSTRIDE (16 * 128)       // 2048 halves  = 4KB
#define WT1_ELEMS (NJ * W1_JSTRIDE)
#define WT2_ELEMS (NJ * W2_JSTRIDE)
#define WT3_ELEMS (NJ * W3_JSTRIDE)
#define WT2_OFF WT1_ELEMS
#define WT3_OFF (WT1_ELEMS + WT2_ELEMS)
#define B3P_BYTE_OFF ((size_t)(WT1_ELEMS + WT2_ELEMS + WT3_ELEMS) * 2)
#define PREP_TOTAL (WT1_ELEMS + WT2_ELEMS + WT3_ELEMS + NJ * 16)

// ---------------------------------------------------------------------------
// Prep: f32 -> f16, chunk-major transposed layouts (proven R2/R4).
// ---------------------------------------------------------------------------
__global__ void posemlp_prep(const float* __restrict__ W1, const float* __restrict__ W2,
                             const float* __restrict__ W3, const float* __restrict__ b3,
                             half_t* __restrict__ wt, float* __restrict__ b3p) {
    int t = blockIdx.x * 256 + threadIdx.x;
    if (t < WT1_ELEMS) {
        int j = t / W1_JSTRIDE, r = t % W1_JSTRIDE;
        int ks = r / 4096, r2 = r % 4096;
        int n = r2 / 32, kk = r2 % 32, k = ks * 32 + kk;
        wt[t] = (half_t)W1[((size_t)j * IN_DIM + k) * HID + n];
    } else if (t < WT2_OFF + WT2_ELEMS) {
        int u = t - WT2_OFF;
        int j = u / W2_JSTRIDE, r = u % W2_JSTRIDE;
        int ks = r / 4096, r2 = r % 4096;
        int n = r2 / 32, kk = r2 % 32, k = ks * 32 + kk;
        wt[t] = (half_t)W2[((size_t)j * HID + k) * HID + n];
    } else if (t < WT3_OFF + WT3_ELEMS) {
        int u = t - WT3_OFF;
        int j = u / W3_JSTRIDE, r = u % W3_JSTRIDE;
        int n = r / 128, k = r % 128;
        wt[t] = (n < OUT_DIM) ? (half_t)W3[((size_t)j * HID + k) * OUT_DIM + n] : (half_t)0.0f;
    } else if (t < PREP_TOTAL) {
        int u = t - WT3_OFF - WT3_ELEMS;
        int j = u / 16, n = u % 16;
        b3p[u] = (n < OUT_DIM) ? b3[j * OUT_DIM + n] : 0.0f;
    }
}

// ---------------------------------------------------------------------------
// helpers
// ---------------------------------------------------------------------------
__device__ inline void gll16(const void* g, void* l) {
    __builtin_amdgcn_global_load_lds(
        (const __attribute__((address_space(1))) unsigned int*)g,
        (__attribute__((address_space(3))) unsigned int*)l, 16, 0, 0);
}

#define VMWAIT(N) asm volatile("s_waitcnt vmcnt(" #N ")" ::: "memory")
#define LGKM0()                                            \
    do {                                                   \
        asm volatile("s_waitcnt lgkmcnt(0)" ::: "memory"); \
        __builtin_amdgcn_sched_barrier(0);                 \
    } while (0)
#define FENCE()                                 \
    do {                                        \
        asm volatile("" ::: "memory");          \
        __builtin_amdgcn_sched_barrier(0);      \
    } while (0)
__device__ inline void barrier_pinned() {
    __builtin_amdgcn_sched_barrier(0);
    __builtin_amdgcn_s_barrier();
    __builtin_amdgcn_sched_barrier(0);
}

// h LDS: [row 0..63][n 0..127] f16, pitch 256B, XOR-swizzled (proven).
__device__ inline half8 lds_read8(const half_t* lds, int r, int k) {
    int byte = r * 256 + k * 2;
    byte ^= (r & 7) << 4;
    return *(const half8*)((const char*)lds + byte);
}
__device__ inline void lds_write4(half_t* lds, int r, int n, half4 v) {
    int byte = r * 256 + n * 2;
    byte ^= (r & 7) << 4;
    *(half4*)((char*)lds + byte) = v;
}

__device__ inline half8 cvt8(floatx4 a, floatx4 b) {
    half8 h;
    h[0] = (_Float16)a[0]; h[1] = (_Float16)a[1]; h[2] = (_Float16)a[2]; h[3] = (_Float16)a[3];
    h[4] = (_Float16)b[0]; h[5] = (_Float16)b[1]; h[6] = (_Float16)b[2]; h[7] = (_Float16)b[3];
    return h;
}

// ---------------------------------------------------------------------------
// Main: 256 threads (4 waves), BM=64 rows.
// VMEM issue order (pinned by fences):
//   [g1-g8]  gll16 W1 k0:4 -> wbuf     [g9] gll16 W3
//   [x1-x16] ALL 8 X chunks -> regs (64 VGPR, stay in flight across barriers)
// Barrier 1: VMWAIT(16) -> drains gll16s ONLY; 16 X loads remain in flight.
// Phase A (ks0-3): compiler inserts exact per-chunk vmcnt for px.
// Barrier 2: stage W1 k4:8, VMWAIT(0) (X4-7 long-arrived by now).
// Phase B (ks4-7), h1 epi; Barrier 3: stage W2, VMWAIT(0); L2, h2 epi, L3.
// ---------------------------------------------------------------------------
__global__ __launch_bounds__(256, 3) void posemlp_main(
    const float* __restrict__ X, const half_t* __restrict__ wt,
    const float* __restrict__ b1, const float* __restrict__ b2,
    const float* __restrict__ b3p, float* __restrict__ out) {
    __shared__ half_t wbuf[16384];     // 32KB: 4 chunks of [n128][kk32]
    __shared__ half_t w3buf[2048];     // 4KB
    __shared__ half_t h_lds[BM * HID]; // 16KB   -> 52KB total, 3 blocks/CU

    const int bid0 = blockIdx.x;
    const int bid = (bid0 & 7) * 768 + (bid0 >> 3);  // XCD swizzle (6144 = 8*768)
    const int j = bid >> 8;
    const int row0 = (bid & 255) * BM;
    const int tid = threadIdx.x;
    const int w = tid >> 6;
    const int l = tid & 63;
    const int lrow = l & 15;
    const int q = l >> 4;
    const int myrow = w * 16 + lrow;

    const float* xq = X + ((size_t)(row0 + myrow) * NJ + j) * IN_DIM + q * 8;

    const half_t* w1j = wt + (size_t)j * W1_JSTRIDE;
    const half_t* w2j = wt + WT2_OFF + (size_t)j * W2_JSTRIDE;
    const half_t* w3j = wt + WT3_OFF + (size_t)j * W3_JSTRIDE;

    // stage-source index (per lane; XOR pre-swizzle on the 16B source slot)
    const int sn = tid >> 2, ss = tid & 3;
    const int wsrc = sn * 32 + (ss ^ ((sn >> 1) & 3)) * 8;  // halves

    // --- prologue: gll16s FIRST (g1-g9), then all X loads (x1-x16) ---
#pragma unroll
    for (int r = 0; r < 8; ++r)
        gll16(w1j + r * 2048 + wsrc, &wbuf[r * 2048 + w * 512]);
    {
        const int tn = tid >> 4, tsl = tid & 15;
        gll16(w3j + tn * 128 + (tsl ^ tn) * 8, &w3buf[w * 512]);
    }
    FENCE();
    floatx4 px[8][2];
#pragma unroll
    for (int c = 0; c < 8; ++c) {
        px[c][0] = *(const floatx4*)(xq + c * 32);
        px[c][1] = *(const floatx4*)(xq + c * 32 + 4);
    }
    FENCE();
    VMWAIT(16);            // g1-g9 done; x1-x16 still in flight
    barrier_pinned();

    // --- phase A: L1 ks=0..3 (compiler emits per-chunk vmcnt for px) ---
    floatx4 acc[8] = {};
#pragma unroll
    for (int ks = 0; ks < 4; ++ks) {
        half8 bx = cvt8(px[ks][0], px[ks][1]);
#pragma unroll
        for (int nf = 0; nf < 8; ++nf) {
            const int n = nf * 16 + lrow;
            half8 a = *(const half8*)&wbuf[ks * 4096 + n * 32 + (q ^ ((n >> 1) & 3)) * 8];
            acc[nf] = __builtin_amdgcn_mfma_f32_16x16x32_f16(a, bx, acc[nf], 0, 0, 0);
        }
    }
    LGKM0();               // this wave's wbuf reads complete
    barrier_pinned();      // all waves done reading W1[k0:4]
#pragma unroll
    for (int r = 0; r < 8; ++r)
        gll16(w1j + 16384 + r * 2048 + wsrc, &wbuf[r * 2048 + w * 512]);
    FENCE();
    VMWAIT(0);             // W1[k4:8] landed (X4-7 arrived during phase A)
    barrier_pinned();

    // --- phase B: L1 ks=4..7 ---
#pragma unroll
    for (int ks = 4; ks < 8; ++ks) {
        half8 bx = cvt8(px[ks][0], px[ks][1]);
#pragma unroll
        for (int nf = 0; nf < 8; ++nf) {
            const int n = nf * 16 + lrow;
            half8 a = *(const half8*)&wbuf[(ks - 4) * 4096 + n * 32 + (q ^ ((n >> 1) & 3)) * 8];
            acc[nf] = __builtin_amdgcn_mfma_f32_16x16x32_f16(a, bx, acc[nf], 0, 0, 0);
        }
    }
    {   // h1 = relu(acc + b1) -> LDS (wave-private rows)
        const float* b1j = b1 + j * HID;
#pragma unroll
        for (int nf = 0; nf < 8; ++nf) {
            floatx4 bb = *(const floatx4*)(b1j + nf * 16 + q * 4);
            floatx4 v = acc[nf];
            half4 hv;
#pragma unroll
            for (int i = 0; i < 4; ++i) hv[i] = (_Float16)fmaxf(v[i] + bb[i], 0.0f);
            lds_write4(h_lds, myrow, nf * 16 + q * 4, hv);
        }
    }
    LGKM0();
    barrier_pinned();      // all waves done reading W1[k4:8]
#pragma unroll
    for (int r = 0; r < 8; ++r)
        gll16(w2j + r * 2048 + wsrc, &wbuf[r * 2048 + w * 512]);
    FENCE();
    VMWAIT(0);
    barrier_pinned();      // W2 landed

    // --- Layer 2: K=128, 4 chunks, all in wbuf ---
    floatx4 acc2[8] = {};
#pragma unroll
    for (int ks = 0; ks < 4; ++ks) {
        half8 bh = lds_read8(h_lds, myrow, ks * 32 + q * 8);
#pragma unroll
        for (int nf = 0; nf < 8; ++nf) {
            const int n = nf * 16 + lrow;
            half8 a = *(const half8*)&wbuf[ks * 4096 + n * 32 + (q ^ ((n >> 1) & 3)) * 8];
            acc2[nf] = __builtin_amdgcn_mfma_f32_16x16x32_f16(a, bh, acc2[nf], 0, 0, 0);
        }
    }
    {   // h2 = relu(acc2 + b2) -> LDS (same wave-private rows)
        const float* b2j = b2 + j * HID;
#pragma unroll
        for (int nf = 0; nf < 8; ++nf) {
            floatx4 bb = *(const floatx4*)(b2j + nf * 16 + q * 4);
            floatx4 v = acc2[nf];
            half4 hv;
#pragma unroll
            for (int i = 0; i < 4; ++i) hv[i] = (_Float16)fmaxf(v[i] + bb[i], 0.0f);
            lds_write4(h_lds, myrow, nf * 16 + q * 4, hv);
        }
    }

    // --- Layer 3: N padded to 16, K=128 ---
    floatx4 acc3 = {};
#pragma unroll
    for (int ks = 0; ks < 4; ++ks) {
        const int u = ks * 4 + q;
        half8 a3 = *(const half8*)&w3buf[lrow * 128 + (u ^ lrow) * 8];
        half8 bh = lds_read8(h_lds, myrow, ks * 32 + q * 8);
        acc3 = __builtin_amdgcn_mfma_f32_16x16x32_f16(a3, bh, acc3, 0, 0, 0);
    }
    {
        floatx4 bb = *(const floatx4*)(b3p + j * 16 + q * 4);
        const int orow = row0 + myrow;
        float* op = out + ((size_t)orow * NJ + j) * OUT_DIM;
        floatx4 v = acc3;
        if (q == 0) {
            float2 s0 = {v[0] + bb[0], v[1] + bb[1]};
            float2 s1 = {v[2] + bb[2], v[3] + bb[3]};
            *(float2*)(op + 0) = s0;
            *(float2*)(op + 2) = s1;
        } else if (q == 1) {
            float2 s = {v[0] + bb[0], v[1] + bb[1]};
            *(float2*)(op + 4) = s;
        }
    }
}

// ---------------------------------------------------------------------------
extern "C" void kernel_launch(void* const* d_in, const int* in_sizes, int n_in,
                              void* d_out, int out_size, void* d_ws, size_t ws_size,
                              hipStream_t stream) {
    const float* X  = (const float*)d_in[0];
    const float* W1 = (const float*)d_in[1];
    const float* b1 = (const float*)d_in[2];
    const float* W2 = (const float*)d_in[3];
    const float* b2 = (const float*)d_in[4];
    const float* W3 = (const float*)d_in[5];
    const float* b3 = (const float*)d_in[6];
    float* out = (float*)d_out;

    half_t* wt = (half_t*)d_ws;
    float* b3p = (float*)((char*)d_ws + B3P_BYTE_OFF);

    int prep_blocks = (PREP_TOTAL + 255) / 256;
    posemlp_prep<<<prep_blocks, 256, 0, stream>>>(W1, W2, W3, b3, wt, b3p);

    int grid = NJ * (BATCH / BM);  // 24 * 256 = 6144
    posemlp_main<<<grid, 256, 0, stream>>>(X, wt, b1, b2, b3p, out);
}